// Round 8
// baseline (228.992 us; speedup 1.0000x reference)
//
#include <hip/hip_runtime.h>
#include <math.h>

#define BG   16
#define NPG  400
#define NN   (BG*NPG)      // 6400 nodes
#define KNN  20
#define NH   8
#define HD   16
#define EM   128
#define NL   3
#define NEGS 0.2f
#define BNEPS 1e-5f
#define MAXDEG 128
#define NSLOT 7            // ceil(400/64) candidates per lane
#define SPAD 16            // floats per BN-stat slot (64B anti-contention padding)
#define KNB  200           // knn blocks (8 waves x 4 nodes = 32 nodes each)
#define MMB  200           // mm tiles (32 rows each)

// ------------- kNN body: one wave per FOUR nodes, interleaved top-20 --------
__device__ __forceinline__ void knn_body4(const float* __restrict__ pos,
                                          int* __restrict__ fwd, int bid) {
    int wave = threadIdx.x >> 6, lane = threadIdx.x & 63;
    int i0 = bid * 32 + wave * 4;        // 4 consecutive nodes, same graph (400%4==0)
    int g = i0 / NPG, l0 = i0 - g * NPG;
    const float* pg = pos + (size_t)g * NPG * 2;

    float cx[4], cy[4];
    #pragma unroll
    for (int n = 0; n < 4; ++n) { cx[n] = pg[(l0 + n) * 2]; cy[n] = pg[(l0 + n) * 2 + 1]; }

    float dl[4][NSLOT];
    #pragma unroll
    for (int s = 0; s < NSLOT; ++s) {
        int j = lane + (s << 6);
        bool valid = j < NPG;
        float px = valid ? pg[j * 2] : 0.f;
        float py = valid ? pg[j * 2 + 1] : 0.f;
        #pragma unroll
        for (int n = 0; n < 4; ++n) {
            float dx = __fsub_rn(cx[n], px);
            float dy = __fsub_rn(cy[n], py);
            float d2 = __fadd_rn(__fmul_rn(dx, dx), __fmul_rn(dy, dy));  // exact np rounding
            dl[n][s] = (valid && j != l0 + n) ? d2 : INFINITY;
        }
    }

    int winj[4] = {0, 0, 0, 0};   // lane r (r<20) holds r-th neighbor of node n
    #pragma unroll 1
    for (int r = 0; r < KNN; ++r) {
        float bv[4]; int bj[4];
        #pragma unroll
        for (int n = 0; n < 4; ++n) {
            float v = dl[n][0]; int bs = 0;
            #pragma unroll
            for (int s = 1; s < NSLOT; ++s)
                if (dl[n][s] < v) { v = dl[n][s]; bs = s; }
            bv[n] = v; bj[n] = lane + (bs << 6);
        }
        #pragma unroll
        for (int off = 32; off > 0; off >>= 1) {
            #pragma unroll
            for (int n = 0; n < 4; ++n) {          // 4 independent chains (ILP)
                float ov = __shfl_xor(bv[n], off);
                int   oj = __shfl_xor(bj[n], off);
                if (ov < bv[n] || (ov == bv[n] && oj < bj[n])) { bv[n] = ov; bj[n] = oj; }
            }
        }
        #pragma unroll
        for (int n = 0; n < 4; ++n) {
            if ((bj[n] & 63) == lane) {            // owner retires winner
                int s = bj[n] >> 6;
                #pragma unroll
                for (int q = 0; q < NSLOT; ++q) if (q == s) dl[n][q] = INFINITY;
            }
            if (lane == r) winj[n] = bj[n];
        }
    }
    if (lane < KNN) {
        #pragma unroll
        for (int n = 0; n < 4; ++n)
            fwd[(size_t)(i0 + n) * KNN + lane] = winj[n];
    }
}

// ---- mm tile (32 rows): [proj | BN+ELU+residual] + hh = h@W + score dots ---
__device__ __forceinline__ void mm_tile(
        int tile, float* __restrict__ h, const float* __restrict__ gout,
        const float* __restrict__ stat, const float* __restrict__ gamma,
        const float* __restrict__ beta, const float* __restrict__ x,
        const float* __restrict__ pw, const float* __restrict__ pb,
        const float* __restrict__ w,
        const float* __restrict__ asrc, const float* __restrict__ adst,
        float* __restrict__ hh, float* __restrict__ ssrc, float* __restrict__ sdst,
        float (*hs)[EM]) {
    int t = threadIdx.x;               // 0..511
    int row0 = tile * 32;
    for (int idx = t; idx < 32 * EM; idx += 512) {
        int r = idx >> 7, c = idx & 127;
        size_t gi = (size_t)(row0 + r) * EM + c;
        float v;
        if (gout) {
            float m  = stat[c * SPAD] * (1.f / NN);
            float vr = stat[(128 + c) * SPAD] * (1.f / NN) - m * m;
            float bnv = (gout[gi] - m) * rsqrtf(vr + BNEPS) * gamma[c] + beta[c];
            bnv = bnv > 0.f ? bnv : expm1f(bnv);   // elu
            v = bnv + h[gi];                        // residual
        } else {
            int n = row0 + r;                       // input projection
            v = x[n * 3 + 0] * pw[c] + x[n * 3 + 1] * pw[EM + c]
              + x[n * 3 + 2] * pw[2 * EM + c] + pb[c];
        }
        h[gi] = v;
        hs[r][c] = v;
    }
    __syncthreads();
    int cc = t & 127, q = t >> 7;
    float acc[8] = {0, 0, 0, 0, 0, 0, 0, 0};
    const float* wp = w + cc;
    for (int k = 0; k < EM; k += 4) {
        float w0 = wp[(k + 0) * EM], w1 = wp[(k + 1) * EM];
        float w2 = wp[(k + 2) * EM], w3 = wp[(k + 3) * EM];
        #pragma unroll
        for (int rr = 0; rr < 8; ++rr) {
            const float4 hv = *(const float4*)&hs[q * 8 + rr][k];
            acc[rr] = fmaf(hv.x, w0, fmaf(hv.y, w1, fmaf(hv.z, w2, fmaf(hv.w, w3, acc[rr]))));
        }
    }
    #pragma unroll
    for (int rr = 0; rr < 8; ++rr)
        hh[(size_t)(row0 + q * 8 + rr) * EM + cc] = acc[rr];
    __syncthreads();
    #pragma unroll
    for (int rr = 0; rr < 8; ++rr) hs[q * 8 + rr][cc] = acc[rr];
    __syncthreads();
    if (t < 32 * NH) {
        int row = t >> 3, hd = t & 7;
        const float* ap = asrc + hd * HD;
        const float* dp = adst + hd * HD;
        float s1 = 0.f, s2 = 0.f;
        #pragma unroll
        for (int d = 0; d < HD; ++d) {
            float v = hs[row][hd * HD + d];
            s1 += v * ap[d]; s2 += v * dp[d];
        }
        ssrc[(size_t)(row0 + row) * NH + hd] = s1;
        sdst[(size_t)(row0 + row) * NH + hd] = s2;
    }
}

// ---- kernel 1: kNN (blocks 0..199)  ||  layer-0 mm (blocks 200..399) -------
__global__ __launch_bounds__(512) void k1_kernel(
        const float* __restrict__ pos, int* __restrict__ fwd,
        float* __restrict__ h, const float* __restrict__ x,
        const float* __restrict__ pw, const float* __restrict__ pb,
        const float* __restrict__ w0,
        const float* __restrict__ asrc0, const float* __restrict__ adst0,
        float* __restrict__ hh, float* __restrict__ ssrc, float* __restrict__ sdst,
        float* __restrict__ statz) {
    __shared__ float hs[32][EM];
    int bid = blockIdx.x;
    if (bid < KNB) {
        knn_body4(pos, fwd, bid);
    } else {
        int tile = bid - KNB;
        if (tile == 0 && threadIdx.x < 256) statz[threadIdx.x * SPAD] = 0.f;
        mm_tile(tile, h, nullptr, nullptr, nullptr, nullptr,
                x, pw, pb, w0, asrc0, adst0, hh, ssrc, sdst, hs);
    }
}

// ---- mm kernel for layers 1,2 (zeroes next stat accumulator) ---------------
__global__ __launch_bounds__(512) void mm_kernel(
        float* __restrict__ h, const float* __restrict__ gout,
        const float* __restrict__ stat, const float* __restrict__ gamma,
        const float* __restrict__ beta, const float* __restrict__ w,
        const float* __restrict__ asrc, const float* __restrict__ adst,
        float* __restrict__ hh, float* __restrict__ ssrc, float* __restrict__ sdst,
        float* __restrict__ statz) {
    __shared__ float hs[32][EM];
    if (blockIdx.x == 0 && threadIdx.x < 256) statz[threadIdx.x * SPAD] = 0.f;
    mm_tile(blockIdx.x, h, gout, stat, gamma, beta,
            nullptr, nullptr, nullptr, w, asrc, adst, hh, ssrc, sdst, hs);
}

// ---- undirected union + self loops; parallel bit extraction ----------------
__global__ __launch_bounds__(1024) void nbr_kernel(const int* __restrict__ fwd,
                                                   int* __restrict__ nbr,
                                                   int* __restrict__ cnt,
                                                   float* __restrict__ out) {
    int g = blockIdx.x, t = threadIdx.x;
    __shared__ unsigned bm[NPG][16];          // 400 x 512 bits = 25.6 KB
    __shared__ unsigned short roff[NPG][13];  // per-row word-start offsets (10.4 KB)
    for (int idx = t; idx < NPG * 16; idx += 1024) ((unsigned*)bm)[idx] = 0u;
    if (t < 128) out[(size_t)NN * EM + g * EM + t] = 0.f;  // zero graph-mean tail
    __syncthreads();
    for (int e = t; e < NPG * KNN; e += 1024) {
        int src = e / KNN;
        int dst = fwd[(size_t)g * NPG * KNN + e];
        atomicOr(&bm[src][dst >> 5], 1u << (dst & 31));
        atomicOr(&bm[dst][src >> 5], 1u << (src & 31));
    }
    if (t < NPG) atomicOr(&bm[t][t >> 5], 1u << (t & 31));  // self loop
    __syncthreads();
    if (t < NPG) {                      // prefix popcounts per row
        int off = 0;
        #pragma unroll
        for (int w = 0; w < 13; ++w) {
            roff[t][w] = (unsigned short)off;
            off += __popc(bm[t][w]);
        }
        cnt[g * NPG + t] = off < MAXDEG ? off : MAXDEG;
    }
    __syncthreads();
    for (int idx = t; idx < NPG * 13; idx += 1024) {   // (row, word) emit tasks
        int row = idx / 13, w = idx - row * 13;
        unsigned m = bm[row][w];
        int c = roff[row][w];
        size_t rbase = (size_t)(g * NPG + row) * MAXDEG;
        int jb = g * NPG + w * 32;
        while (m) {
            int b = __ffs(m) - 1;
            m &= m - 1;
            if (c < MAXDEG) nbr[rbase + c++] = jb + b;
        }
    }
}

// ---- attention (wave/node, LDS-staged ssrc) + fused BN-stat accumulation ---
__global__ __launch_bounds__(512) void attn_kernel(const float* __restrict__ hh,
                                                   const int* __restrict__ nbrl,
                                                   const int* __restrict__ cnt,
                                                   const float* __restrict__ ssrc,
                                                   const float* __restrict__ sdst,
                                                   const float* __restrict__ bias,
                                                   float* __restrict__ gout,
                                                   float* __restrict__ statl) {
    __shared__ float smem[8 * 1152 + NPG * NH + 256];  // sc/nb + ssl + red = 50.7 KB
    int widb = threadIdx.x >> 6, lane = threadIdx.x & 63;
    float* sc  = smem + widb * 1152;
    int*   nb  = (int*)(sc + 1024);
    float* ssl = smem + 8 * 1152;
    float* red = ssl + NPG * NH;
    int i = blockIdx.x * 8 + widb;           // one node per wave; same graph per block
    int g = (blockIdx.x * 8) / NPG, base = g * NPG;

    // stage this graph's ssrc table (400x8 floats) + zero stat partials
    for (int idx = threadIdx.x; idx < NPG * NH / 4; idx += 512)
        ((float4*)ssl)[idx] = ((const float4*)(ssrc + (size_t)base * NH))[idx];
    if (threadIdx.x < 256) red[threadIdx.x] = 0.f;
    __syncthreads();

    int c = cnt[i];
    for (int j = lane; j < c; j += 64) nb[j] = nbrl[(size_t)i * MAXDEG + j];
    asm volatile("s_waitcnt lgkmcnt(0)" ::: "memory");
    int hd = lane & 7, sub = lane >> 3;
    float sd = sdst[i * NH + hd];
    for (int idx = lane; idx < c * NH; idx += 64) {   // idx&7 == lane&7
        int jj = idx >> 3;
        float v = sd + ssl[(nb[jj] - base) * NH + hd];
        sc[idx] = v >= 0.f ? v : NEGS * v;            // leaky_relu
    }
    asm volatile("s_waitcnt lgkmcnt(0)" ::: "memory");
    float mx = -INFINITY;
    for (int jj = sub; jj < c; jj += 8) mx = fmaxf(mx, sc[jj * 8 + hd]);
    #pragma unroll
    for (int off = 8; off < 64; off <<= 1) mx = fmaxf(mx, __shfl_xor(mx, off));
    float s = 0.f;
    for (int jj = sub; jj < c; jj += 8) {
        float e = expf(sc[jj * 8 + hd] - mx);
        sc[jj * 8 + hd] = e;
        s += e;
    }
    #pragma unroll
    for (int off = 8; off < 64; off <<= 1) s += __shfl_xor(s, off);
    float inv = 1.f / s;                     // lane k (k<8) holds inv for head k
    asm volatile("s_waitcnt lgkmcnt(0)" ::: "memory");

    // PV: lane owns channels (2*lane, 2*lane+1); both in head h0 = lane>>3
    int h0 = lane >> 3;
    float invh = __shfl(inv, h0);
    float acc0 = 0.f, acc1 = 0.f;
    for (int jj = 0; jj < c; jj += 2) {
        float a0 = sc[jj * 8 + h0];
        float2 p0 = *(const float2*)(hh + (size_t)nb[jj] * EM + 2 * lane);
        int j1 = (jj + 1 < c) ? jj + 1 : jj;
        float a1 = (jj + 1 < c) ? sc[(jj + 1) * 8 + h0] : 0.f;
        float2 p1 = *(const float2*)(hh + (size_t)nb[j1] * EM + 2 * lane);
        acc0 += a0 * p0.x + a1 * p1.x;
        acc1 += a0 * p0.y + a1 * p1.y;
    }
    float2 bv = *(const float2*)(bias + 2 * lane);
    float v0 = acc0 * invh + bv.x;
    float v1 = acc1 * invh + bv.y;
    float2 ov; ov.x = v0; ov.y = v1;
    *(float2*)(gout + (size_t)i * EM + 2 * lane) = ov;

    // BN stat partials: channels 2*lane (v0), 2*lane+1 (v1)
    atomicAdd(&red[2 * lane], v0);
    atomicAdd(&red[2 * lane + 1], v1);
    atomicAdd(&red[128 + 2 * lane], v0 * v0);
    atomicAdd(&red[128 + 2 * lane + 1], v1 * v1);
    __syncthreads();
    if (threadIdx.x < 256)
        atomicAdd(&statl[threadIdx.x * SPAD], red[threadIdx.x]);
}

// ---- final: BN+ELU+residual (layer 2) -> node out + graph-mean atomics -----
__global__ __launch_bounds__(256) void finish_kernel(const float* __restrict__ gout,
                                                     const float* __restrict__ stat,
                                                     const float* __restrict__ gamma,
                                                     const float* __restrict__ beta,
                                                     const float* __restrict__ h,
                                                     float* __restrict__ out) {
    int b = blockIdx.x;          // 16 graphs x 8 chunks of 50 rows
    int g = b >> 3, ch = b & 7;
    int t = threadIdx.x, c = t & 127, half = t >> 7;
    float m  = stat[c * SPAD] * (1.f / NN);
    float vr = stat[(128 + c) * SPAD] * (1.f / NN) - m * m;
    float rs = rsqrtf(vr + BNEPS);
    float ga = gamma[c], be = beta[c];
    int r0 = g * NPG + ch * 50;
    float s = 0.f;
    for (int k = half; k < 50; k += 2) {
        size_t gi = (size_t)(r0 + k) * EM + c;
        float v = (gout[gi] - m) * rs * ga + be;
        v = v > 0.f ? v : expm1f(v);
        v += h[gi];
        out[gi] = v;
        s += v;
    }
    __shared__ float l1[256];
    l1[t] = s;
    __syncthreads();
    if (half == 0)
        atomicAdd(&out[(size_t)NN * EM + g * EM + c], (l1[c] + l1[c + 128]) * (1.f / NPG));
}

extern "C" void kernel_launch(void* const* d_in, const int* in_sizes, int n_in,
                              void* d_out, int out_size, void* d_ws, size_t ws_size,
                              hipStream_t stream) {
    const float* x      = (const float*)d_in[0];
    const float* pos    = (const float*)d_in[1];
    // d_in[2] = batch (int32), unused: graphs are contiguous blocks of 400
    const float* proj_w = (const float*)d_in[3];
    const float* proj_b = (const float*)d_in[4];
    const float* lin_w  = (const float*)d_in[5];
    const float* asrc   = (const float*)d_in[6];
    const float* adst   = (const float*)d_in[7];
    const float* gbias  = (const float*)d_in[8];
    const float* gamma  = (const float*)d_in[9];
    const float* beta   = (const float*)d_in[10];
    float* out = (float*)d_out;

    char* p = (char*)d_ws;
    auto take = [&](size_t bytes) { char* q = p; p += (bytes + 63) & ~(size_t)63; return q; };
    int*   fwd  = (int*)take((size_t)NN * KNN * 4);
    int*   nbrl = (int*)take((size_t)NN * MAXDEG * 4);
    int*   cnt  = (int*)take((size_t)NN * 4);
    float* h    = (float*)take((size_t)NN * EM * 4);
    float* hh   = (float*)take((size_t)NN * EM * 4);
    float* gout = (float*)take((size_t)NN * EM * 4);
    float* ssrc = (float*)take((size_t)NN * NH * 4);
    float* sdst = (float*)take((size_t)NN * NH * 4);
    float* statA = (float*)take((size_t)256 * SPAD * 4);
    float* statB = (float*)take((size_t)256 * SPAD * 4);
    float* statv[2] = {statA, statB};

    // 1: kNN || layer-0 mm (+zero statv[0])
    k1_kernel<<<KNB + MMB, 512, 0, stream>>>(pos, fwd, h, x, proj_w, proj_b,
                                             lin_w, asrc, adst, hh, ssrc, sdst,
                                             statv[0]);
    // 2: adjacency lists (+zero out tail)
    nbr_kernel<<<BG, 1024, 0, stream>>>(fwd, nbrl, cnt, out);
    // 3: attn layer 0 -> statv[0]
    attn_kernel<<<NN / 8, 512, 0, stream>>>(hh, nbrl, cnt, ssrc, sdst,
                                            gbias, gout, statv[0]);
    // 4: mm layer 1 (reads statv[0], zeroes statv[1])
    mm_kernel<<<MMB, 512, 0, stream>>>(h, gout, statv[0], gamma, beta,
                                       lin_w + (size_t)EM * EM, asrc + EM, adst + EM,
                                       hh, ssrc, sdst, statv[1]);
    // 5: attn layer 1 -> statv[1]
    attn_kernel<<<NN / 8, 512, 0, stream>>>(hh, nbrl, cnt, ssrc, sdst,
                                            gbias + EM, gout, statv[1]);
    // 6: mm layer 2 (reads statv[1], zeroes statv[0])
    mm_kernel<<<MMB, 512, 0, stream>>>(h, gout, statv[1], gamma + EM, beta + EM,
                                       lin_w + (size_t)2 * EM * EM, asrc + 2 * EM, adst + 2 * EM,
                                       hh, ssrc, sdst, statv[0]);
    // 7: attn layer 2 -> statv[0]
    attn_kernel<<<NN / 8, 512, 0, stream>>>(hh, nbrl, cnt, ssrc, sdst,
                                            gbias + 2 * EM, gout, statv[0]);
    // 8: finish
    finish_kernel<<<BG * 8, 256, 0, stream>>>(gout, statv[0],
                                              gamma + 2 * EM, beta + 2 * EM, h, out);
}

// Round 9
// 190.872 us; speedup vs baseline: 1.1997x; 1.1997x over previous
//
#include <hip/hip_runtime.h>
#include <math.h>

#define BG   16
#define NPG  400
#define NN   (BG*NPG)      // 6400 nodes
#define KNN  20
#define NH   8
#define HD   16
#define EM   128
#define NL   3
#define NEGS 0.2f
#define BNEPS 1e-5f
#define MAXDEG 128
#define NSLOT 7            // ceil(400/64) candidates per lane
#define SPAD 16            // floats per BN-stat slot (64B anti-contention padding)
#define KNB  800           // knn blocks (8 waves x 1 node each)
#define MMB  200           // mm tiles (32 rows each)

// ------- kNN: wave per node, RADIX-SELECT top-20 (ballot counting) ----------
// Set of 20 smallest (d2_bits, j) pairs == jax top_k(-d2) selection set.
__device__ __forceinline__ void knn_radix(const float* __restrict__ pos,
                                          int* __restrict__ fwd, int bid,
                                          int* __restrict__ ctr) {
    int wave = threadIdx.x >> 6, lane = threadIdx.x & 63;
    int i = bid * 8 + wave;             // global node
    int g = i / NPG, li = i - g * NPG;  // graph, local index
    const float* pg = pos + (size_t)g * NPG * 2;
    float xi = pg[li * 2], yi = pg[li * 2 + 1];

    unsigned kk[NSLOT], kx[NSLOT];      // key bits; key ^ prefix
    #pragma unroll
    for (int s = 0; s < NSLOT; ++s) {
        int j = lane + (s << 6);
        unsigned kb = 0x7F800000u;      // +inf for invalid/self
        if (j < NPG && j != li) {
            float dx = __fsub_rn(xi, pg[j * 2]);
            float dy = __fsub_rn(yi, pg[j * 2 + 1]);
            float d2 = __fadd_rn(__fmul_rn(dx, dx), __fmul_rn(dy, dy));  // exact np rounding
            kb = __float_as_uint(d2);
        }
        kk[s] = kb; kx[s] = kb;
    }

    // MSB radix select: after loop, P = 20th-smallest key; R = #needed among ==P
    unsigned P = 0; int R = KNN;
    #pragma unroll
    for (int bit = 29; bit >= 0; --bit) {
        int c = 0;
        #pragma unroll
        for (int s = 0; s < NSLOT; ++s)
            c += __popcll(__ballot(kx[s] < (1u << bit)));   // in-prefix AND bit==0
        unsigned delta = (R > c) ? (1u << bit) : 0u;
        R -= (R > c) ? c : 0;
        P |= delta;
        #pragma unroll
        for (int s = 0; s < NSLOT; ++s) kx[s] ^= delta;
    }

    bool sel[NSLOT];
    int nsel = 0;
    #pragma unroll
    for (int s = 0; s < NSLOT; ++s) { sel[s] = kk[s] < P; nsel += sel[s] ? 1 : 0; }

    // ties at threshold (kx==0 <=> kk==P): take R smallest j (j unique per slot)
    #pragma unroll 1
    while (R > 0) {
        int bj = 0x7FFFFFFF;
        #pragma unroll
        for (int s = 0; s < NSLOT; ++s)
            if (kx[s] == 0 && !sel[s]) { int j = lane + (s << 6); bj = j < bj ? j : bj; }
        int m = bj;
        #pragma unroll
        for (int off = 32; off > 0; off >>= 1) { int o = __shfl_xor(m, off); m = o < m ? o : m; }
        if (bj == m && bj != 0x7FFFFFFF) {
            #pragma unroll
            for (int s = 0; s < NSLOT; ++s)
                if ((lane + (s << 6)) == bj) { sel[s] = true; nsel++; }
        }
        R--;
    }

    // emit (order-free): per-wave LDS counter gives write offsets
    if (lane == 0) ctr[wave] = 0;
    int pos0 = atomicAdd(&ctr[wave], nsel);
    int w = 0;
    #pragma unroll
    for (int s = 0; s < NSLOT; ++s)
        if (sel[s]) { fwd[(size_t)i * KNN + pos0 + w] = lane + (s << 6); ++w; }
}

// ---- mm tile (32 rows): [proj | BN+ELU+residual] + hh = h@W + score dots ---
__device__ __forceinline__ void mm_tile(
        int tile, float* __restrict__ h, const float* __restrict__ gout,
        const float* __restrict__ stat, const float* __restrict__ gamma,
        const float* __restrict__ beta, const float* __restrict__ x,
        const float* __restrict__ pw, const float* __restrict__ pb,
        const float* __restrict__ w,
        const float* __restrict__ asrc, const float* __restrict__ adst,
        float* __restrict__ hh, float* __restrict__ ssrc, float* __restrict__ sdst,
        float (*hs)[EM]) {
    int t = threadIdx.x;               // 0..511
    int row0 = tile * 32;
    for (int idx = t; idx < 32 * EM; idx += 512) {
        int r = idx >> 7, c = idx & 127;
        size_t gi = (size_t)(row0 + r) * EM + c;
        float v;
        if (gout) {
            float m  = stat[c * SPAD] * (1.f / NN);
            float vr = stat[(128 + c) * SPAD] * (1.f / NN) - m * m;
            float bnv = (gout[gi] - m) * rsqrtf(vr + BNEPS) * gamma[c] + beta[c];
            bnv = bnv > 0.f ? bnv : expm1f(bnv);   // elu
            v = bnv + h[gi];                        // residual
        } else {
            int n = row0 + r;                       // input projection
            v = x[n * 3 + 0] * pw[c] + x[n * 3 + 1] * pw[EM + c]
              + x[n * 3 + 2] * pw[2 * EM + c] + pb[c];
        }
        h[gi] = v;
        hs[r][c] = v;
    }
    __syncthreads();
    int cc = t & 127, q = t >> 7;
    float acc[8] = {0, 0, 0, 0, 0, 0, 0, 0};
    const float* wp = w + cc;
    for (int k = 0; k < EM; k += 4) {
        float w0 = wp[(k + 0) * EM], w1 = wp[(k + 1) * EM];
        float w2 = wp[(k + 2) * EM], w3 = wp[(k + 3) * EM];
        #pragma unroll
        for (int rr = 0; rr < 8; ++rr) {
            const float4 hv = *(const float4*)&hs[q * 8 + rr][k];
            acc[rr] = fmaf(hv.x, w0, fmaf(hv.y, w1, fmaf(hv.z, w2, fmaf(hv.w, w3, acc[rr]))));
        }
    }
    #pragma unroll
    for (int rr = 0; rr < 8; ++rr)
        hh[(size_t)(row0 + q * 8 + rr) * EM + cc] = acc[rr];
    __syncthreads();
    #pragma unroll
    for (int rr = 0; rr < 8; ++rr) hs[q * 8 + rr][cc] = acc[rr];
    __syncthreads();
    if (t < 32 * NH) {
        int row = t >> 3, hd = t & 7;
        const float* ap = asrc + hd * HD;
        const float* dp = adst + hd * HD;
        float s1 = 0.f, s2 = 0.f;
        #pragma unroll
        for (int d = 0; d < HD; ++d) {
            float v = hs[row][hd * HD + d];
            s1 += v * ap[d]; s2 += v * dp[d];
        }
        ssrc[(size_t)(row0 + row) * NH + hd] = s1;
        sdst[(size_t)(row0 + row) * NH + hd] = s2;
    }
}

// ---- kernel 1: kNN (blocks 0..799)  ||  layer-0 mm (blocks 800..999) -------
__global__ __launch_bounds__(512) void k1_kernel(
        const float* __restrict__ pos, int* __restrict__ fwd,
        float* __restrict__ h, const float* __restrict__ x,
        const float* __restrict__ pw, const float* __restrict__ pb,
        const float* __restrict__ w0,
        const float* __restrict__ asrc0, const float* __restrict__ adst0,
        float* __restrict__ hh, float* __restrict__ ssrc, float* __restrict__ sdst,
        float* __restrict__ statz) {
    __shared__ float hs[32][EM];
    __shared__ int ctr[8];
    int bid = blockIdx.x;
    if (bid < KNB) {
        knn_radix(pos, fwd, bid, ctr);
    } else {
        int tile = bid - KNB;
        if (tile == 0 && threadIdx.x < 256) statz[threadIdx.x * SPAD] = 0.f;
        mm_tile(tile, h, nullptr, nullptr, nullptr, nullptr,
                x, pw, pb, w0, asrc0, adst0, hh, ssrc, sdst, hs);
    }
}

// ---- mm kernel for layers 1,2 (zeroes next stat accumulator) ---------------
__global__ __launch_bounds__(512) void mm_kernel(
        float* __restrict__ h, const float* __restrict__ gout,
        const float* __restrict__ stat, const float* __restrict__ gamma,
        const float* __restrict__ beta, const float* __restrict__ w,
        const float* __restrict__ asrc, const float* __restrict__ adst,
        float* __restrict__ hh, float* __restrict__ ssrc, float* __restrict__ sdst,
        float* __restrict__ statz) {
    __shared__ float hs[32][EM];
    if (blockIdx.x == 0 && threadIdx.x < 256) statz[threadIdx.x * SPAD] = 0.f;
    mm_tile(blockIdx.x, h, gout, stat, gamma, beta,
            nullptr, nullptr, nullptr, w, asrc, adst, hh, ssrc, sdst, hs);
}

// ---- undirected union + self loops; parallel bit extraction ----------------
__global__ __launch_bounds__(1024) void nbr_kernel(const int* __restrict__ fwd,
                                                   int* __restrict__ nbr,
                                                   int* __restrict__ cnt,
                                                   float* __restrict__ out) {
    int g = blockIdx.x, t = threadIdx.x;
    __shared__ unsigned bm[NPG][16];          // 400 x 512 bits = 25.6 KB
    __shared__ unsigned short roff[NPG][13];  // per-row word-start offsets
    for (int idx = t; idx < NPG * 16; idx += 1024) ((unsigned*)bm)[idx] = 0u;
    if (t < 128) out[(size_t)NN * EM + g * EM + t] = 0.f;  // zero graph-mean tail
    __syncthreads();
    for (int e = t; e < NPG * KNN; e += 1024) {
        int src = e / KNN;
        int dst = fwd[(size_t)g * NPG * KNN + e];
        atomicOr(&bm[src][dst >> 5], 1u << (dst & 31));
        atomicOr(&bm[dst][src >> 5], 1u << (src & 31));
    }
    if (t < NPG) atomicOr(&bm[t][t >> 5], 1u << (t & 31));  // self loop
    __syncthreads();
    if (t < NPG) {                      // prefix popcounts per row
        int off = 0;
        #pragma unroll
        for (int w = 0; w < 13; ++w) {
            roff[t][w] = (unsigned short)off;
            off += __popc(bm[t][w]);
        }
        cnt[g * NPG + t] = off < MAXDEG ? off : MAXDEG;
    }
    __syncthreads();
    for (int idx = t; idx < NPG * 13; idx += 1024) {   // (row, word) emit tasks
        int row = idx / 13, w = idx - row * 13;
        unsigned m = bm[row][w];
        int c = roff[row][w];
        size_t rbase = (size_t)(g * NPG + row) * MAXDEG;
        int jb = g * NPG + w * 32;
        while (m) {
            int b = __ffs(m) - 1;
            m &= m - 1;
            if (c < MAXDEG) nbr[rbase + c++] = jb + b;
        }
    }
}

// ---- attention (wave per node, float2 channels) + fused BN-stat accum ------
__global__ __launch_bounds__(512) void attn_kernel(const float* __restrict__ hh,
                                                   const int* __restrict__ nbrl,
                                                   const int* __restrict__ cnt,
                                                   const float* __restrict__ ssrc,
                                                   const float* __restrict__ sdst,
                                                   const float* __restrict__ bias,
                                                   float* __restrict__ gout,
                                                   float* __restrict__ statl) {
    __shared__ float smem[8 * 1152 + 256];   // per-wave: 1024 scores + 128 nbr ints
    int widb = threadIdx.x >> 6, lane = threadIdx.x & 63;
    float* sc = smem + widb * 1152;
    int*   nb = (int*)(sc + 1024);
    float* red = smem + 8 * 1152;
    int i = blockIdx.x * 8 + widb;           // one node per wave, exact cover

    if (threadIdx.x < 256) red[threadIdx.x] = 0.f;
    __syncthreads();

    int c = cnt[i];
    for (int j = lane; j < c; j += 64) nb[j] = nbrl[(size_t)i * MAXDEG + j];
    asm volatile("s_waitcnt lgkmcnt(0)" ::: "memory");
    int hd = lane & 7, sub = lane >> 3;
    float sd = sdst[i * NH + hd];
    for (int idx = lane; idx < c * NH; idx += 64) {   // idx&7 == lane&7
        int jj = idx >> 3;
        float v = sd + ssrc[nb[jj] * NH + hd];
        sc[idx] = v >= 0.f ? v : NEGS * v;            // leaky_relu
    }
    asm volatile("s_waitcnt lgkmcnt(0)" ::: "memory");
    float mx = -INFINITY;
    for (int jj = sub; jj < c; jj += 8) mx = fmaxf(mx, sc[jj * 8 + hd]);
    #pragma unroll
    for (int off = 8; off < 64; off <<= 1) mx = fmaxf(mx, __shfl_xor(mx, off));
    float s = 0.f;
    for (int jj = sub; jj < c; jj += 8) {
        float e = expf(sc[jj * 8 + hd] - mx);
        sc[jj * 8 + hd] = e;
        s += e;
    }
    #pragma unroll
    for (int off = 8; off < 64; off <<= 1) s += __shfl_xor(s, off);
    float inv = 1.f / s;                     // lane k (k<8) holds inv for head k
    asm volatile("s_waitcnt lgkmcnt(0)" ::: "memory");

    // PV: lane owns channels (2*lane, 2*lane+1); both in head h0 = lane>>3
    int h0 = lane >> 3;
    float invh = __shfl(inv, h0);
    float acc0 = 0.f, acc1 = 0.f;
    for (int jj = 0; jj < c; jj += 2) {
        float a0 = sc[jj * 8 + h0];
        float2 p0 = *(const float2*)(hh + (size_t)nb[jj] * EM + 2 * lane);
        int j1 = (jj + 1 < c) ? jj + 1 : jj;
        float a1 = (jj + 1 < c) ? sc[(jj + 1) * 8 + h0] : 0.f;
        float2 p1 = *(const float2*)(hh + (size_t)nb[j1] * EM + 2 * lane);
        acc0 += a0 * p0.x + a1 * p1.x;
        acc1 += a0 * p0.y + a1 * p1.y;
    }
    float2 bv = *(const float2*)(bias + 2 * lane);
    float v0 = acc0 * invh + bv.x;
    float v1 = acc1 * invh + bv.y;
    float2 ov; ov.x = v0; ov.y = v1;
    *(float2*)(gout + (size_t)i * EM + 2 * lane) = ov;

    // BN stat partials: channels 2*lane (v0), 2*lane+1 (v1)
    atomicAdd(&red[2 * lane], v0);
    atomicAdd(&red[2 * lane + 1], v1);
    atomicAdd(&red[128 + 2 * lane], v0 * v0);
    atomicAdd(&red[128 + 2 * lane + 1], v1 * v1);
    __syncthreads();
    if (threadIdx.x < 256)
        atomicAdd(&statl[threadIdx.x * SPAD], red[threadIdx.x]);
}

// ---- final: BN+ELU+residual (layer 2) -> node out + graph-mean atomics -----
__global__ __launch_bounds__(256) void finish_kernel(const float* __restrict__ gout,
                                                     const float* __restrict__ stat,
                                                     const float* __restrict__ gamma,
                                                     const float* __restrict__ beta,
                                                     const float* __restrict__ h,
                                                     float* __restrict__ out) {
    int b = blockIdx.x;          // 16 graphs x 8 chunks of 50 rows
    int g = b >> 3, ch = b & 7;
    int t = threadIdx.x, c = t & 127, half = t >> 7;
    float m  = stat[c * SPAD] * (1.f / NN);
    float vr = stat[(128 + c) * SPAD] * (1.f / NN) - m * m;
    float rs = rsqrtf(vr + BNEPS);
    float ga = gamma[c], be = beta[c];
    int r0 = g * NPG + ch * 50;
    float s = 0.f;
    for (int k = half; k < 50; k += 2) {
        size_t gi = (size_t)(r0 + k) * EM + c;
        float v = (gout[gi] - m) * rs * ga + be;
        v = v > 0.f ? v : expm1f(v);
        v += h[gi];
        out[gi] = v;
        s += v;
    }
    __shared__ float l1[256];
    l1[t] = s;
    __syncthreads();
    if (half == 0)
        atomicAdd(&out[(size_t)NN * EM + g * EM + c], (l1[c] + l1[c + 128]) * (1.f / NPG));
}

extern "C" void kernel_launch(void* const* d_in, const int* in_sizes, int n_in,
                              void* d_out, int out_size, void* d_ws, size_t ws_size,
                              hipStream_t stream) {
    const float* x      = (const float*)d_in[0];
    const float* pos    = (const float*)d_in[1];
    // d_in[2] = batch (int32), unused: graphs are contiguous blocks of 400
    const float* proj_w = (const float*)d_in[3];
    const float* proj_b = (const float*)d_in[4];
    const float* lin_w  = (const float*)d_in[5];
    const float* asrc   = (const float*)d_in[6];
    const float* adst   = (const float*)d_in[7];
    const float* gbias  = (const float*)d_in[8];
    const float* gamma  = (const float*)d_in[9];
    const float* beta   = (const float*)d_in[10];
    float* out = (float*)d_out;

    char* p = (char*)d_ws;
    auto take = [&](size_t bytes) { char* q = p; p += (bytes + 63) & ~(size_t)63; return q; };
    int*   fwd  = (int*)take((size_t)NN * KNN * 4);
    int*   nbrl = (int*)take((size_t)NN * MAXDEG * 4);
    int*   cnt  = (int*)take((size_t)NN * 4);
    float* h    = (float*)take((size_t)NN * EM * 4);
    float* hh   = (float*)take((size_t)NN * EM * 4);
    float* gout = (float*)take((size_t)NN * EM * 4);
    float* ssrc = (float*)take((size_t)NN * NH * 4);
    float* sdst = (float*)take((size_t)NN * NH * 4);
    float* statA = (float*)take((size_t)256 * SPAD * 4);
    float* statB = (float*)take((size_t)256 * SPAD * 4);
    float* statv[2] = {statA, statB};

    // 1: kNN (radix-select) || layer-0 mm (+zero statv[0])
    k1_kernel<<<KNB + MMB, 512, 0, stream>>>(pos, fwd, h, x, proj_w, proj_b,
                                             lin_w, asrc, adst, hh, ssrc, sdst,
                                             statv[0]);
    // 2: adjacency lists (+zero out tail)
    nbr_kernel<<<BG, 1024, 0, stream>>>(fwd, nbrl, cnt, out);
    // 3: attn layer 0 -> statv[0]
    attn_kernel<<<NN / 8, 512, 0, stream>>>(hh, nbrl, cnt, ssrc, sdst,
                                            gbias, gout, statv[0]);
    // 4: mm layer 1 (reads statv[0], zeroes statv[1])
    mm_kernel<<<MMB, 512, 0, stream>>>(h, gout, statv[0], gamma, beta,
                                       lin_w + (size_t)EM * EM, asrc + EM, adst + EM,
                                       hh, ssrc, sdst, statv[1]);
    // 5: attn layer 1 -> statv[1]
    attn_kernel<<<NN / 8, 512, 0, stream>>>(hh, nbrl, cnt, ssrc, sdst,
                                            gbias + EM, gout, statv[1]);
    // 6: mm layer 2 (reads statv[1], zeroes statv[0])
    mm_kernel<<<MMB, 512, 0, stream>>>(h, gout, statv[1], gamma + EM, beta + EM,
                                       lin_w + (size_t)2 * EM * EM, asrc + 2 * EM, adst + 2 * EM,
                                       hh, ssrc, sdst, statv[0]);
    // 7: attn layer 2 -> statv[0]
    attn_kernel<<<NN / 8, 512, 0, stream>>>(hh, nbrl, cnt, ssrc, sdst,
                                            gbias + 2 * EM, gout, statv[0]);
    // 8: finish
    finish_kernel<<<BG * 8, 256, 0, stream>>>(gout, statv[0],
                                              gamma + 2 * EM, beta + 2 * EM, h, out);
}